// Round 1
// baseline (513.393 us; speedup 1.0000x reference)
//
#include <hip/hip_runtime.h>
#include <hip/hip_bf16.h>
#include <cstdint>

typedef __bf16 bf16;
typedef __attribute__((ext_vector_type(8))) __bf16 bf16x8;
typedef __attribute__((ext_vector_type(4))) float f32x4;

__device__ __forceinline__ float silu_f(float x) { return x * (1.f / (1.f + __expf(-x))); }

// ---------------- ws layout ----------------
// bf16 weight arena (element offsets into (bf16*)ws)
constexpr long WB_IPW1 = 0;          // 256*192
constexpr long WB_IPW2 = 49152;      // 256*256
constexpr long WB_QKV  = 114688;     // 3*768*256
constexpr long WB_WO   = 704512;     // 3*256*256
constexpr long WB_W1   = 901120;     // 3*1024*256
constexpr long WB_W2   = 1687552;    // 3*256*1024
constexpr long WB_DPW1 = 2473984;    // 256*512
constexpr long WB_DPW2 = 2605056;    // 256*256
constexpr long WB_CPW1 = 2670592;    // 256*256
// float buffers (byte offsets into ws)
constexpr long F_ZIN = 5472256;                 // 512*192 f32
constexpr long F_G   = F_ZIN + 512L*192*4;      // 256 f32
constexpr long F_H   = F_G + 1024;              // 512*256 f32
constexpr long F_QKV = F_H + 512L*256*4;        // 512*768 f32
constexpr long F_S   = F_QKV + 512L*768*4;      // 4*512*512 f32 (also ff1)
constexpr long F_VT  = F_S + 4L*512*512*4;      // 4*64*512 bf16
constexpr long F_O   = F_VT + 4L*64*512*2;      // 512*256 f32
constexpr long F_T1  = F_O + 512L*256*4;        // 512*256 f32
constexpr long F_AI  = F_T1 + 512L*256*4;       // 512*256 f32
constexpr long F_AJ  = F_AI + 512L*256*4;       // 512*256 f32

// ---------------- weight fp32 -> bf16 conversion ----------------
__global__ __launch_bounds__(256) void convw_kernel(
    const float* __restrict__ s_ipw1, const float* __restrict__ s_ipw2,
    const float* __restrict__ s_qkv,  const float* __restrict__ s_wo,
    const float* __restrict__ s_w1,   const float* __restrict__ s_w2,
    const float* __restrict__ s_dpw1, const float* __restrict__ s_dpw2,
    const float* __restrict__ s_cpw1, bf16* __restrict__ dst)
{
  long v = (long)blockIdx.x * 256 + threadIdx.x;   // vec4 index, total 684032
  if (v >= 684032) return;
  const float* src; long off;
  if (v < 176128) {
    if (v < 12288)      { src = s_ipw1; off = 0; }
    else if (v < 28672) { src = s_ipw2; off = 12288; }
    else                { src = s_qkv;  off = 28672; }
  } else if (v < 618496) {
    if (v < 225280)      { src = s_wo; off = 176128; }
    else if (v < 421888) { src = s_w1; off = 225280; }
    else                 { src = s_w2; off = 421888; }
  } else {
    if (v < 651264)      { src = s_dpw1; off = 618496; }
    else if (v < 667648) { src = s_dpw2; off = 651264; }
    else                 { src = s_cpw1; off = 667648; }
  }
  long e = (v - off) * 4;
  float4 f = *(const float4*)&src[e];
  bf16* d = dst + off * 4 + e;
  d[0] = (bf16)f.x; d[1] = (bf16)f.y; d[2] = (bf16)f.z; d[3] = (bf16)f.w;
}

// ---------------- build z_input = concat(z, emb[atom_types]) ----------------
__global__ __launch_bounds__(256) void zin_kernel(
    const float* __restrict__ z, const int* __restrict__ at,
    const float* __restrict__ emb, float* __restrict__ zi)
{
  int idx = blockIdx.x * 256 + threadIdx.x;  // < 512*192
  int n = idx / 192, c = idx - n * 192;
  zi[idx] = (c < 128) ? z[n * 128 + c] : emb[at[n] * 64 + (c - 128)];
}

// ---------------- global-feature MLP (tiny) ----------------
__global__ __launch_bounds__(256) void gproj_kernel(
    const float* __restrict__ zg, const float* __restrict__ w1, const float* __restrict__ b1,
    const float* __restrict__ w2, const float* __restrict__ b2, float* __restrict__ g)
{
  __shared__ float zs[128];
  __shared__ float ts[256];
  int tid = threadIdx.x;
  if (tid < 128) zs[tid] = zg[tid];
  __syncthreads();
  float s = b1[tid];
  for (int k = 0; k < 128; ++k) s += zs[k] * w1[tid * 128 + k];
  ts[tid] = silu_f(s);
  __syncthreads();
  float s2 = b2[tid];
  for (int k = 0; k < 256; ++k) s2 += ts[k] * w2[tid * 256 + k];
  g[tid] = s2;
}

// ---------------- generic MFMA GEMM: C = act(A @ W^T + bias) (+R) ----------------
// A: fp32 [M,K] lda ; W: (bf16|fp32) [N,K] ldw ; C: fp32 ldc ; R: optional residual (ldr may be 0)
template<int ACT, typename WT>
__global__ __launch_bounds__(256) void gemm_kernel(
    const float* __restrict__ A, int lda, long sA,
    const WT* __restrict__ W, int ldw, long sW,
    const float* __restrict__ bias,
    const float* __restrict__ R, int ldr, long sR,
    float* __restrict__ C, int ldc, long sC, int K)
{
  const int bz = blockIdx.z;
  A += (long)bz * sA;  W += (long)bz * sW;  C += (long)bz * sC;
  if (R) R += (long)bz * sR;
  const int m0 = blockIdx.x * 64, n0 = blockIdx.y * 64;
  __shared__ bf16 As[64][72];
  __shared__ bf16 Ws[64][72];
  const int tid = threadIdx.x;
  const int lane = tid & 63, wid = tid >> 6;
  const int wm = (wid & 1) * 32, wn = (wid >> 1) * 32;
  const int rr = lane & 15, kg = (lane >> 4) << 3;
  f32x4 acc[2][2] = {};
  for (int k0 = 0; k0 < K; k0 += 64) {
#pragma unroll
    for (int r = 0; r < 4; ++r) {
      int lin = tid + r * 256;
      int row = lin >> 4, kc = (lin & 15) << 2;
      {
        const float* p = &A[(long)(m0 + row) * lda + k0 + kc];
        float4 v = *(const float4*)p;
        As[row][kc] = (bf16)v.x; As[row][kc + 1] = (bf16)v.y;
        As[row][kc + 2] = (bf16)v.z; As[row][kc + 3] = (bf16)v.w;
      }
      {
        const WT* p = &W[(long)(n0 + row) * ldw + k0 + kc];
        if constexpr (sizeof(WT) == 4) {
          float4 v = *(const float4*)p;
          Ws[row][kc] = (bf16)v.x; Ws[row][kc + 1] = (bf16)v.y;
          Ws[row][kc + 2] = (bf16)v.z; Ws[row][kc + 3] = (bf16)v.w;
        } else {
          *(uint2*)&Ws[row][kc] = *(const uint2*)p;
        }
      }
    }
    __syncthreads();
#pragma unroll
    for (int ks = 0; ks < 2; ++ks) {
      const int kk = ks * 32 + kg;
      bf16x8 a0 = *(const bf16x8*)&As[wm + rr][kk];
      bf16x8 a1 = *(const bf16x8*)&As[wm + 16 + rr][kk];
      bf16x8 b0 = *(const bf16x8*)&Ws[wn + rr][kk];
      bf16x8 b1 = *(const bf16x8*)&Ws[wn + 16 + rr][kk];
      acc[0][0] = __builtin_amdgcn_mfma_f32_16x16x32_bf16(a0, b0, acc[0][0], 0, 0, 0);
      acc[0][1] = __builtin_amdgcn_mfma_f32_16x16x32_bf16(a0, b1, acc[0][1], 0, 0, 0);
      acc[1][0] = __builtin_amdgcn_mfma_f32_16x16x32_bf16(a1, b0, acc[1][0], 0, 0, 0);
      acc[1][1] = __builtin_amdgcn_mfma_f32_16x16x32_bf16(a1, b1, acc[1][1], 0, 0, 0);
    }
    __syncthreads();
  }
  const int rg = lane >> 4;
#pragma unroll
  for (int mi = 0; mi < 2; ++mi)
#pragma unroll
    for (int ni = 0; ni < 2; ++ni)
#pragma unroll
      for (int r = 0; r < 4; ++r) {
        int gm = m0 + wm + mi * 16 + rg * 4 + r;
        int gn = n0 + wn + ni * 16 + rr;
        float v = acc[mi][ni][r];
        if (bias) v += bias[gn];
        if (R) v += R[(long)gm * ldr + gn];
        if (ACT == 1) v = silu_f(v);
        else if (ACT == 2) v = fmaxf(v, 0.f);
        C[(long)gm * ldc + gn] = v;
      }
}

// ---------------- row softmax over S (4,512,512), scale=1/8 ----------------
__global__ __launch_bounds__(256) void softmax_kernel(float* __restrict__ S)
{
  long base = ((long)blockIdx.y * 512 + blockIdx.x) * 512;
  float* row = S + base;
  int tid = threadIdx.x;
  float a = row[tid] * 0.125f, b = row[tid + 256] * 0.125f;
  float m = fmaxf(a, b);
#pragma unroll
  for (int o = 1; o < 64; o <<= 1) m = fmaxf(m, __shfl_xor(m, o));
  __shared__ float red[4];
  __shared__ float red2[4];
  int wid = tid >> 6;
  if ((tid & 63) == 0) red[wid] = m;
  __syncthreads();
  m = fmaxf(fmaxf(red[0], red[1]), fmaxf(red[2], red[3]));
  float e0 = __expf(a - m), e1 = __expf(b - m);
  float s = e0 + e1;
#pragma unroll
  for (int o = 1; o < 64; o <<= 1) s += __shfl_xor(s, o);
  if ((tid & 63) == 0) red2[wid] = s;
  __syncthreads();
  s = red2[0] + red2[1] + red2[2] + red2[3];
  float inv = 1.f / s;
  row[tid] = e0 * inv; row[tid + 256] = e1 * inv;
}

// ---------------- V transpose -> Vt[h][d][n] (bf16) ----------------
__global__ __launch_bounds__(256) void vt_kernel(const float* __restrict__ qkv, bf16* __restrict__ vt)
{
  int idx = blockIdx.x * 256 + threadIdx.x;   // < 131072
  int hh = idx >> 15;
  int r = idx & 32767;
  int d = r >> 9, n = r & 511;
  vt[idx] = (bf16)qkv[(long)n * 768 + 512 + hh * 64 + d];
}

// ---------------- LayerNorm rows of 256 ----------------
__global__ __launch_bounds__(256) void ln_kernel(
    const float* __restrict__ X, const float* __restrict__ sc,
    const float* __restrict__ bi, float* __restrict__ Y)
{
  int row = blockIdx.x, tid = threadIdx.x;
  float v = X[(long)row * 256 + tid];
  float s = v;
#pragma unroll
  for (int o = 1; o < 64; o <<= 1) s += __shfl_xor(s, o);
  __shared__ float r1[4];
  __shared__ float r2[4];
  if ((tid & 63) == 0) r1[tid >> 6] = s;
  __syncthreads();
  float mean = (r1[0] + r1[1] + r1[2] + r1[3]) * (1.f / 256.f);
  float d = v - mean;
  float t = d * d;
#pragma unroll
  for (int o = 1; o < 64; o <<= 1) t += __shfl_xor(t, o);
  if ((tid & 63) == 0) r2[tid >> 6] = t;
  __syncthreads();
  float var = (r2[0] + r2[1] + r2[2] + r2[3]) * (1.f / 256.f);
  Y[(long)row * 256 + tid] = d * rsqrtf(var + 1e-5f) * sc[tid] + bi[tid];
}

// ---------------- fused pair/dist kernel ----------------
// per block: 32x32 (i,j) tile; per step: 2 i-rows x 32 j => M=64 MFMA rows
__global__ __launch_bounds__(256) void pair_kernel(
    const float* __restrict__ ai, const float* __restrict__ aj,
    const bf16* __restrict__ W2, const float* __restrict__ b2g,
    const float* __restrict__ w3g, const float* __restrict__ b3p,
    float* __restrict__ dout)
{
  __shared__ float aj_s[32][256];
  __shared__ bf16 t_s[64][264];
  __shared__ float ai_s[2][256];
  __shared__ float b2_s[256];
  __shared__ float w3_s[256];
  __shared__ float part[64][4];
  const int tid = threadIdx.x, lane = tid & 63, w = tid >> 6;
  const int i0 = blockIdx.x * 32, j0 = blockIdx.y * 32;
  const float b3v = b3p[0];
  // stage aj tile + b2 + w3
#pragma unroll
  for (int r = 0; r < 8; ++r) {
    int lin = tid + r * 256;
    int row = lin >> 6, c4 = (lin & 63) << 2;
    *(float4*)&aj_s[row][c4] = *(const float4*)&aj[(long)(j0 + row) * 256 + c4];
  }
  b2_s[tid] = b2g[tid];
  w3_s[tid] = w3g[tid];
  const int rr = lane & 15, kg = (lane >> 4) << 3, rg = lane >> 4;
  for (int it = 0; it < 16; ++it) {
    int ibase = i0 + it * 2;
    ai_s[0][tid] = ai[(long)ibase * 256 + tid];
    ai_s[1][tid] = ai[(long)(ibase + 1) * 256 + tid];
    __syncthreads();   // S1: ai_s/aj_s ready, prev iter fully done
#pragma unroll 16
    for (int p = 0; p < 64; ++p) {
      float v = ai_s[p >> 5][tid] + aj_s[p & 31][tid];
      t_s[p][tid] = (bf16)silu_f(v);
    }
    __syncthreads();   // S2: t ready
    f32x4 acc[4][4] = {};
#pragma unroll
    for (int k0 = 0; k0 < 256; k0 += 32) {
      const int kk = k0 + kg;
      bf16x8 af[4];
#pragma unroll
      for (int mi = 0; mi < 4; ++mi) af[mi] = *(const bf16x8*)&t_s[mi * 16 + rr][kk];
#pragma unroll
      for (int ni = 0; ni < 4; ++ni) {
        bf16x8 bfv = *(const bf16x8*)&W2[(long)(w * 64 + ni * 16 + rr) * 256 + kk];
#pragma unroll
        for (int mi = 0; mi < 4; ++mi)
          acc[mi][ni] = __builtin_amdgcn_mfma_f32_16x16x32_bf16(af[mi], bfv, acc[mi][ni], 0, 0, 0);
      }
    }
    // epilogue: silu(pre_u + b2) * w3, reduce over n
#pragma unroll
    for (int mi = 0; mi < 4; ++mi)
#pragma unroll
      for (int r = 0; r < 4; ++r) {
        float s = 0.f;
#pragma unroll
        for (int ni = 0; ni < 4; ++ni) {
          int n = w * 64 + ni * 16 + rr;
          float u = acc[mi][ni][r] + b2_s[n];
          s += silu_f(u) * w3_s[n];
        }
        s += __shfl_xor(s, 1); s += __shfl_xor(s, 2);
        s += __shfl_xor(s, 4); s += __shfl_xor(s, 8);
        if (rr == 0) part[mi * 16 + rg * 4 + r][w] = s;
      }
    __syncthreads();   // S3: part ready
    if (tid < 64) {
      float s = part[tid][0] + part[tid][1] + part[tid][2] + part[tid][3] + b3v;
      float dd = fmaxf(s, 0.f) + log1pf(__expf(-fabsf(s)));
      int ii = ibase + (tid >> 5);
      int jj = j0 + (tid & 31);
      dout[(long)ii * 512 + jj] = dd;
    }
  }
}

// ---------------- symmetrize dist in place ----------------
__global__ __launch_bounds__(256) void sym_kernel(float* __restrict__ dist)
{
  int idx = blockIdx.x * 256 + threadIdx.x;   // < 262144
  int i = idx >> 9, j = idx & 511;
  if (i < j) {
    float a = dist[idx];
    float b = dist[(long)j * 512 + i];
    float m = 0.5f * (a + b);
    dist[idx] = m;
    dist[(long)j * 512 + i] = m;
  }
}

// ---------------- coordinate head final 256->3 ----------------
__global__ __launch_bounds__(256) void coord_kernel(
    const float* __restrict__ ct, const float* __restrict__ w2,
    const float* __restrict__ b2, float* __restrict__ out)
{
  int t = blockIdx.x * 256 + threadIdx.x;
  if (t >= 1536) return;
  int row = t / 3, c = t - row * 3;
  float s = b2[c];
  const float* a = &ct[(long)row * 256];
  const float* wp = &w2[c * 256];
  for (int k = 0; k < 256; ++k) s += a[k] * wp[k];
  out[t] = s;
}

extern "C" void kernel_launch(void* const* d_in, const int* in_sizes, int n_in,
                              void* d_out, int out_size, void* d_ws, size_t ws_size,
                              hipStream_t stream) {
  const float* z        = (const float*)d_in[0];
  const float* z_global = (const float*)d_in[1];
  const int*   atom_t   = (const int*)d_in[2];
  const float* emb      = (const float*)d_in[3];
  const float* ip_w1 = (const float*)d_in[4];  const float* ip_b1 = (const float*)d_in[5];
  const float* ip_w2 = (const float*)d_in[6];  const float* ip_b2 = (const float*)d_in[7];
  const float* gp_w1 = (const float*)d_in[8];  const float* gp_b1 = (const float*)d_in[9];
  const float* gp_w2 = (const float*)d_in[10]; const float* gp_b2 = (const float*)d_in[11];
  const float* wqkv  = (const float*)d_in[12]; const float* bqkv  = (const float*)d_in[13];
  const float* wo    = (const float*)d_in[14]; const float* bo    = (const float*)d_in[15];
  const float* ln1s  = (const float*)d_in[16]; const float* ln1b  = (const float*)d_in[17];
  const float* w1    = (const float*)d_in[18]; const float* b1    = (const float*)d_in[19];
  const float* w2    = (const float*)d_in[20]; const float* b2    = (const float*)d_in[21];
  const float* ln2s  = (const float*)d_in[22]; const float* ln2b  = (const float*)d_in[23];
  const float* dpw1  = (const float*)d_in[24]; const float* dpb1  = (const float*)d_in[25];
  const float* dpw2  = (const float*)d_in[26]; const float* dpb2  = (const float*)d_in[27];
  const float* dpw3  = (const float*)d_in[28]; const float* dpb3  = (const float*)d_in[29];
  const float* cpw1  = (const float*)d_in[30]; const float* cpb1  = (const float*)d_in[31];
  const float* cpw2  = (const float*)d_in[32]; const float* cpb2  = (const float*)d_in[33];

  char* ws = (char*)d_ws;
  bf16*  WB  = (bf16*)ws;
  float* zin = (float*)(ws + F_ZIN);
  float* g   = (float*)(ws + F_G);
  float* h   = (float*)(ws + F_H);
  float* qkv = (float*)(ws + F_QKV);
  float* S   = (float*)(ws + F_S);
  bf16*  Vt  = (bf16*)(ws + F_VT);
  float* o   = (float*)(ws + F_O);
  float* t1  = (float*)(ws + F_T1);
  float* ai  = (float*)(ws + F_AI);
  float* aj  = (float*)(ws + F_AJ);
  float* ff1 = S;  // reuse
  float* out  = (float*)d_out;
  float* xout = out;
  float* dist = out + 1536;

  convw_kernel<<<2672, 256, 0, stream>>>(ip_w1, ip_w2, wqkv, wo, w1, w2, dpw1, dpw2, cpw1, WB);
  zin_kernel<<<384, 256, 0, stream>>>(z, atom_t, emb, zin);
  gproj_kernel<<<1, 256, 0, stream>>>(z_global, gp_w1, gp_b1, gp_w2, gp_b2, g);
  // t1 = silu(zin @ ip_w1^T + b1)
  gemm_kernel<1, bf16><<<dim3(8, 4, 1), 256, 0, stream>>>(zin, 192, 0, WB + WB_IPW1, 192, 0,
      ip_b1, nullptr, 0, 0, t1, 256, 0, 192);
  // h = t1 @ ip_w2^T + b2 + g (broadcast residual, ldr=0)
  gemm_kernel<0, bf16><<<dim3(8, 4, 1), 256, 0, stream>>>(t1, 256, 0, WB + WB_IPW2, 256, 0,
      ip_b2, g, 0, 0, h, 256, 0, 256);

  for (int l = 0; l < 3; ++l) {
    const bf16* wq = WB + WB_QKV + (long)l * 768 * 256;
    gemm_kernel<0, bf16><<<dim3(8, 12, 1), 256, 0, stream>>>(h, 256, 0, wq, 256, 0,
        bqkv + l * 768, nullptr, 0, 0, qkv, 768, 0, 256);
    // S[h] = q @ k^T (batched over 4 heads), both fp32 slices of qkv
    gemm_kernel<0, float><<<dim3(8, 8, 4), 256, 0, stream>>>(qkv, 768, 64, qkv + 256, 768, 64,
        nullptr, nullptr, 0, 0, S, 512, 262144, 64);
    softmax_kernel<<<dim3(512, 4), 256, 0, stream>>>(S);
    vt_kernel<<<512, 256, 0, stream>>>(qkv, Vt);
    // o[:, h*64:(h+1)*64] = P @ V
    gemm_kernel<0, bf16><<<dim3(8, 1, 4), 256, 0, stream>>>(S, 512, 262144, Vt, 512, 32768,
        nullptr, nullptr, 0, 0, o, 256, 64, 512);
    gemm_kernel<0, bf16><<<dim3(8, 4, 1), 256, 0, stream>>>(o, 256, 0,
        WB + WB_WO + (long)l * 65536, 256, 0, bo + l * 256, h, 256, 0, t1, 256, 0, 256);
    ln_kernel<<<512, 256, 0, stream>>>(t1, ln1s + l * 256, ln1b + l * 256, h);
    gemm_kernel<2, bf16><<<dim3(8, 16, 1), 256, 0, stream>>>(h, 256, 0,
        WB + WB_W1 + (long)l * 262144, 256, 0, b1 + l * 1024, nullptr, 0, 0, ff1, 1024, 0, 256);
    gemm_kernel<0, bf16><<<dim3(8, 4, 1), 256, 0, stream>>>(ff1, 1024, 0,
        WB + WB_W2 + (long)l * 262144, 1024, 0, b2 + l * 256, h, 256, 0, t1, 256, 0, 1024);
    ln_kernel<<<512, 256, 0, stream>>>(t1, ln2s + l * 256, ln2b + l * 256, h);
  }

  // ai = h @ dp_w1[:, :256]^T + b1 ; aj = h @ dp_w1[:, 256:]^T
  gemm_kernel<0, bf16><<<dim3(8, 4, 1), 256, 0, stream>>>(h, 256, 0, WB + WB_DPW1, 512, 0,
      dpb1, nullptr, 0, 0, ai, 256, 0, 256);
  gemm_kernel<0, bf16><<<dim3(8, 4, 1), 256, 0, stream>>>(h, 256, 0, WB + WB_DPW1 + 256, 512, 0,
      nullptr, nullptr, 0, 0, aj, 256, 0, 256);
  pair_kernel<<<dim3(16, 16), 256, 0, stream>>>(ai, aj, WB + WB_DPW2, dpb2, dpw3, dpb3, dist);
  sym_kernel<<<1024, 256, 0, stream>>>(dist);
  // coord head
  gemm_kernel<1, bf16><<<dim3(8, 4, 1), 256, 0, stream>>>(h, 256, 0, WB + WB_CPW1, 256, 0,
      cpb1, nullptr, 0, 0, t1, 256, 0, 256);
  coord_kernel<<<6, 256, 0, stream>>>(t1, cpw2, cpb2, xout);
}

// Round 2
// 416.021 us; speedup vs baseline: 1.2341x; 1.2341x over previous
//
#include <hip/hip_runtime.h>
#include <hip/hip_bf16.h>
#include <cstdint>

typedef __bf16 bf16;
typedef __attribute__((ext_vector_type(8))) __bf16 bf16x8;
typedef __attribute__((ext_vector_type(4))) float f32x4;

__device__ __forceinline__ float silu_f(float x) { return x * (1.f / (1.f + __expf(-x))); }

// ---------------- ws layout ----------------
// bf16 weight arena (element offsets into (bf16*)ws)
constexpr long WB_IPW1 = 0;          // 256*192
constexpr long WB_IPW2 = 49152;      // 256*256
constexpr long WB_QKV  = 114688;     // 3*768*256
constexpr long WB_WO   = 704512;     // 3*256*256
constexpr long WB_W1   = 901120;     // 3*1024*256
constexpr long WB_W2   = 1687552;    // 3*256*1024
constexpr long WB_DPW1 = 2473984;    // 256*512
constexpr long WB_DPW2 = 2605056;    // 256*256
constexpr long WB_CPW1 = 2670592;    // 256*256
// float buffers (byte offsets into ws)
constexpr long F_ZIN = 5472256;                 // 512*192 f32
constexpr long F_G   = F_ZIN + 512L*192*4;      // 256 f32
constexpr long F_H   = F_G + 1024;              // 512*256 f32
constexpr long F_QKV = F_H + 512L*256*4;        // 512*768 f32
constexpr long F_S   = F_QKV + 512L*768*4;      // 4*512*512 f32 (also ff1; later W2P)
constexpr long F_VT  = F_S + 4L*512*512*4;      // 4*64*512 bf16
constexpr long F_O   = F_VT + 4L*64*512*2;      // 512*256 f32
constexpr long F_T1  = F_O + 512L*256*4;        // 512*256 f32
constexpr long F_AI  = F_T1 + 512L*256*4;       // 512*256 f32
constexpr long F_AJ  = F_AI + 512L*256*4;       // 512*256 f32

// ---------------- weight fp32 -> bf16 conversion ----------------
__global__ __launch_bounds__(256) void convw_kernel(
    const float* __restrict__ s_ipw1, const float* __restrict__ s_ipw2,
    const float* __restrict__ s_qkv,  const float* __restrict__ s_wo,
    const float* __restrict__ s_w1,   const float* __restrict__ s_w2,
    const float* __restrict__ s_dpw1, const float* __restrict__ s_dpw2,
    const float* __restrict__ s_cpw1, bf16* __restrict__ dst)
{
  long v = (long)blockIdx.x * 256 + threadIdx.x;   // vec4 index, total 684032
  if (v >= 684032) return;
  const float* src; long off;
  if (v < 176128) {
    if (v < 12288)      { src = s_ipw1; off = 0; }
    else if (v < 28672) { src = s_ipw2; off = 12288; }
    else                { src = s_qkv;  off = 28672; }
  } else if (v < 618496) {
    if (v < 225280)      { src = s_wo; off = 176128; }
    else if (v < 421888) { src = s_w1; off = 225280; }
    else                 { src = s_w2; off = 421888; }
  } else {
    if (v < 651264)      { src = s_dpw1; off = 618496; }
    else if (v < 667648) { src = s_dpw2; off = 651264; }
    else                 { src = s_cpw1; off = 667648; }
  }
  long e = (v - off) * 4;
  float4 f = *(const float4*)&src[e];
  bf16* d = dst + off * 4 + e;
  d[0] = (bf16)f.x; d[1] = (bf16)f.y; d[2] = (bf16)f.z; d[3] = (bf16)f.w;
}

// ---------------- build z_input = concat(z, emb[atom_types]) ----------------
__global__ __launch_bounds__(256) void zin_kernel(
    const float* __restrict__ z, const int* __restrict__ at,
    const float* __restrict__ emb, float* __restrict__ zi)
{
  int idx = blockIdx.x * 256 + threadIdx.x;  // < 512*192
  int n = idx / 192, c = idx - n * 192;
  zi[idx] = (c < 128) ? z[n * 128 + c] : emb[at[n] * 64 + (c - 128)];
}

// ---------------- global-feature MLP (tiny) ----------------
__global__ __launch_bounds__(256) void gproj_kernel(
    const float* __restrict__ zg, const float* __restrict__ w1, const float* __restrict__ b1,
    const float* __restrict__ w2, const float* __restrict__ b2, float* __restrict__ g)
{
  __shared__ float zs[128];
  __shared__ float ts[256];
  int tid = threadIdx.x;
  if (tid < 128) zs[tid] = zg[tid];
  __syncthreads();
  float s = b1[tid];
  for (int k = 0; k < 128; ++k) s += zs[k] * w1[tid * 128 + k];
  ts[tid] = silu_f(s);
  __syncthreads();
  float s2 = b2[tid];
  for (int k = 0; k < 256; ++k) s2 += ts[k] * w2[tid * 256 + k];
  g[tid] = s2;
}

// ---------------- generic MFMA GEMM: C = act(A @ W^T + bias) (+R) ----------------
template<int ACT, typename WT>
__global__ __launch_bounds__(256) void gemm_kernel(
    const float* __restrict__ A, int lda, long sA,
    const WT* __restrict__ W, int ldw, long sW,
    const float* __restrict__ bias,
    const float* __restrict__ R, int ldr, long sR,
    float* __restrict__ C, int ldc, long sC, int K)
{
  const int bz = blockIdx.z;
  A += (long)bz * sA;  W += (long)bz * sW;  C += (long)bz * sC;
  if (R) R += (long)bz * sR;
  const int m0 = blockIdx.x * 64, n0 = blockIdx.y * 64;
  __shared__ bf16 As[64][72];
  __shared__ bf16 Ws[64][72];
  const int tid = threadIdx.x;
  const int lane = tid & 63, wid = tid >> 6;
  const int wm = (wid & 1) * 32, wn = (wid >> 1) * 32;
  const int rr = lane & 15, kg = (lane >> 4) << 3;
  f32x4 acc[2][2] = {};
  for (int k0 = 0; k0 < K; k0 += 64) {
#pragma unroll
    for (int r = 0; r < 4; ++r) {
      int lin = tid + r * 256;
      int row = lin >> 4, kc = (lin & 15) << 2;
      {
        const float* p = &A[(long)(m0 + row) * lda + k0 + kc];
        float4 v = *(const float4*)p;
        As[row][kc] = (bf16)v.x; As[row][kc + 1] = (bf16)v.y;
        As[row][kc + 2] = (bf16)v.z; As[row][kc + 3] = (bf16)v.w;
      }
      {
        const WT* p = &W[(long)(n0 + row) * ldw + k0 + kc];
        if constexpr (sizeof(WT) == 4) {
          float4 v = *(const float4*)p;
          Ws[row][kc] = (bf16)v.x; Ws[row][kc + 1] = (bf16)v.y;
          Ws[row][kc + 2] = (bf16)v.z; Ws[row][kc + 3] = (bf16)v.w;
        } else {
          *(uint2*)&Ws[row][kc] = *(const uint2*)p;
        }
      }
    }
    __syncthreads();
#pragma unroll
    for (int ks = 0; ks < 2; ++ks) {
      const int kk = ks * 32 + kg;
      bf16x8 a0 = *(const bf16x8*)&As[wm + rr][kk];
      bf16x8 a1 = *(const bf16x8*)&As[wm + 16 + rr][kk];
      bf16x8 b0 = *(const bf16x8*)&Ws[wn + rr][kk];
      bf16x8 b1 = *(const bf16x8*)&Ws[wn + 16 + rr][kk];
      acc[0][0] = __builtin_amdgcn_mfma_f32_16x16x32_bf16(a0, b0, acc[0][0], 0, 0, 0);
      acc[0][1] = __builtin_amdgcn_mfma_f32_16x16x32_bf16(a0, b1, acc[0][1], 0, 0, 0);
      acc[1][0] = __builtin_amdgcn_mfma_f32_16x16x32_bf16(a1, b0, acc[1][0], 0, 0, 0);
      acc[1][1] = __builtin_amdgcn_mfma_f32_16x16x32_bf16(a1, b1, acc[1][1], 0, 0, 0);
    }
    __syncthreads();
  }
  const int rg = lane >> 4;
#pragma unroll
  for (int mi = 0; mi < 2; ++mi)
#pragma unroll
    for (int ni = 0; ni < 2; ++ni)
#pragma unroll
      for (int r = 0; r < 4; ++r) {
        int gm = m0 + wm + mi * 16 + rg * 4 + r;
        int gn = n0 + wn + ni * 16 + rr;
        float v = acc[mi][ni][r];
        if (bias) v += bias[gn];
        if (R) v += R[(long)gm * ldr + gn];
        if (ACT == 1) v = silu_f(v);
        else if (ACT == 2) v = fmaxf(v, 0.f);
        C[(long)gm * ldc + gn] = v;
      }
}

// ---------------- row softmax over S (4,512,512), scale=1/8 ----------------
__global__ __launch_bounds__(256) void softmax_kernel(float* __restrict__ S)
{
  long base = ((long)blockIdx.y * 512 + blockIdx.x) * 512;
  float* row = S + base;
  int tid = threadIdx.x;
  float a = row[tid] * 0.125f, b = row[tid + 256] * 0.125f;
  float m = fmaxf(a, b);
#pragma unroll
  for (int o = 1; o < 64; o <<= 1) m = fmaxf(m, __shfl_xor(m, o));
  __shared__ float red[4];
  __shared__ float red2[4];
  int wid = tid >> 6;
  if ((tid & 63) == 0) red[wid] = m;
  __syncthreads();
  m = fmaxf(fmaxf(red[0], red[1]), fmaxf(red[2], red[3]));
  float e0 = __expf(a - m), e1 = __expf(b - m);
  float s = e0 + e1;
#pragma unroll
  for (int o = 1; o < 64; o <<= 1) s += __shfl_xor(s, o);
  if ((tid & 63) == 0) red2[wid] = s;
  __syncthreads();
  s = red2[0] + red2[1] + red2[2] + red2[3];
  float inv = 1.f / s;
  row[tid] = e0 * inv; row[tid + 256] = e1 * inv;
}

// ---------------- V transpose -> Vt[h][d][n] (bf16) ----------------
__global__ __launch_bounds__(256) void vt_kernel(const float* __restrict__ qkv, bf16* __restrict__ vt)
{
  int idx = blockIdx.x * 256 + threadIdx.x;   // < 131072
  int hh = idx >> 15;
  int r = idx & 32767;
  int d = r >> 9, n = r & 511;
  vt[idx] = (bf16)qkv[(long)n * 768 + 512 + hh * 64 + d];
}

// ---------------- LayerNorm rows of 256 ----------------
__global__ __launch_bounds__(256) void ln_kernel(
    const float* __restrict__ X, const float* __restrict__ sc,
    const float* __restrict__ bi, float* __restrict__ Y)
{
  int row = blockIdx.x, tid = threadIdx.x;
  float v = X[(long)row * 256 + tid];
  float s = v;
#pragma unroll
  for (int o = 1; o < 64; o <<= 1) s += __shfl_xor(s, o);
  __shared__ float r1[4];
  __shared__ float r2[4];
  if ((tid & 63) == 0) r1[tid >> 6] = s;
  __syncthreads();
  float mean = (r1[0] + r1[1] + r1[2] + r1[3]) * (1.f / 256.f);
  float d = v - mean;
  float t = d * d;
#pragma unroll
  for (int o = 1; o < 64; o <<= 1) t += __shfl_xor(t, o);
  if ((tid & 63) == 0) r2[tid >> 6] = t;
  __syncthreads();
  float var = (r2[0] + r2[1] + r2[2] + r2[3]) * (1.f / 256.f);
  Y[(long)row * 256 + tid] = d * rsqrtf(var + 1e-5f) * sc[tid] + bi[tid];
}

// ---------------- W2 permute to MFMA B-fragment-linear layout ----------------
// frag f = ((nt*8 + ks)*4 + kq)*16 + l15  ->  src W2[n = nt*16+l15][k = ks*32+kq*8 .. +7]
__global__ __launch_bounds__(256) void permw2_kernel(
    const bf16* __restrict__ w2b, bf16* __restrict__ w2p)
{
  int f = blockIdx.x * 256 + threadIdx.x;   // 8192 frags
  int l15 = f & 15, kq = (f >> 4) & 3, ks = (f >> 6) & 7, nt = f >> 9;
  int n = nt * 16 + l15, k0 = ks * 32 + kq * 8;
  uint4 v = *(const uint4*)&w2b[n * 256 + k0];
  *(uint4*)&w2p[(long)f * 8] = v;
}

// ---------------- fused pair/dist kernel v2 ----------------
// grid 512 (one block per i-row), 256 threads = 4 waves.
// Wave w handles n-range [w*64, w*64+64) (4 n-tiles of 16). W2 frags held in
// registers for the whole kernel. Loop over 8 j-chunks of 64 pairs:
//   build t = silu(ai+aj) into LDS in fragment-linear layout (conflict-free),
//   MFMA 64x64x256 per wave, epilogue silu(u+b2)*w3 + shfl reduce over n,
//   cross-wave combine in LDS, softplus, write dist row.
__global__ __launch_bounds__(256, 2) void pair2_kernel(
    const float* __restrict__ ai, const float* __restrict__ aj,
    const bf16* __restrict__ W2P, const float* __restrict__ b2g,
    const float* __restrict__ w3g, const float* __restrict__ b3p,
    float* __restrict__ dout)
{
  __shared__ float ai_s[256];
  __shared__ bf16  t_s[64 * 256];     // (kk*64 + p)*8 + e, kk = k/8 (32KB)
  __shared__ float part[64][4];
  const int tid = threadIdx.x, lane = tid & 63, w = tid >> 6;
  const int l15 = lane & 15, kq = lane >> 4;    // kq in 0..3
  const int i = blockIdx.x;
  const float b3v = b3p[0];

  ai_s[tid] = ai[(long)i * 256 + tid];

  // preload W2 fragments for this wave's n-range: nt 0..3 (global nt = w*4+nt), ks 0..7
  bf16x8 w2r[4][8];
  float b2v[4], w3v[4];
#pragma unroll
  for (int nt = 0; nt < 4; ++nt) {
    int ntg = w * 4 + nt;
#pragma unroll
    for (int ks = 0; ks < 8; ++ks)
      w2r[nt][ks] = *(const bf16x8*)&W2P[(long)((((ntg * 8 + ks) * 4 + kq) * 16) + l15) * 8];
    b2v[nt] = b2g[ntg * 16 + l15];
    w3v[nt] = w3g[ntg * 16 + l15];
  }
  __syncthreads();

  const float* ajrow = aj + (long)lane * 256;   // + j0*256 per chunk
  for (int jc = 0; jc < 8; ++jc) {
    const int j0 = jc * 64;
    // ---- build t: each thread: pair p = lane, kk = w + 4r (8 chunks of 8 k) ----
    const float* ajp = ajrow + (long)j0 * 256;
#pragma unroll
    for (int r = 0; r < 8; ++r) {
      int kk = w + 4 * r;
      float4 a0 = *(const float4*)(ajp + kk * 8);
      float4 a1 = *(const float4*)(ajp + kk * 8 + 4);
      const float* aip = ai_s + kk * 8;
      bf16x8 tv;
      tv[0] = (bf16)silu_f(a0.x + aip[0]); tv[1] = (bf16)silu_f(a0.y + aip[1]);
      tv[2] = (bf16)silu_f(a0.z + aip[2]); tv[3] = (bf16)silu_f(a0.w + aip[3]);
      tv[4] = (bf16)silu_f(a1.x + aip[4]); tv[5] = (bf16)silu_f(a1.y + aip[5]);
      tv[6] = (bf16)silu_f(a1.z + aip[6]); tv[7] = (bf16)silu_f(a1.w + aip[7]);
      *(bf16x8*)&t_s[(kk * 64 + lane) * 8] = tv;
    }
    __syncthreads();   // t ready

    // ---- MFMA: M=64 (4 Mt of 16), N=64 (4 nt), K=256 (8 ks of 32) ----
    f32x4 acc[4][4] = {};
#pragma unroll
    for (int ks = 0; ks < 8; ++ks) {
      bf16x8 af[4];
#pragma unroll
      for (int Mt = 0; Mt < 4; ++Mt)
        af[Mt] = *(const bf16x8*)&t_s[((ks * 4 + kq) * 64 + Mt * 16 + l15) * 8];
#pragma unroll
      for (int nt = 0; nt < 4; ++nt)
#pragma unroll
        for (int Mt = 0; Mt < 4; ++Mt)
          acc[Mt][nt] = __builtin_amdgcn_mfma_f32_16x16x32_bf16(af[Mt], w2r[nt][ks], acc[Mt][nt], 0, 0, 0);
    }

    // ---- epilogue: s = sum_n silu(u + b2)*w3 over this wave's 64 n ----
#pragma unroll
    for (int Mt = 0; Mt < 4; ++Mt)
#pragma unroll
      for (int r = 0; r < 4; ++r) {
        float s = silu_f(acc[Mt][0][r] + b2v[0]) * w3v[0]
                + silu_f(acc[Mt][1][r] + b2v[1]) * w3v[1]
                + silu_f(acc[Mt][2][r] + b2v[2]) * w3v[2]
                + silu_f(acc[Mt][3][r] + b2v[3]) * w3v[3];
        s += __shfl_xor(s, 1); s += __shfl_xor(s, 2);
        s += __shfl_xor(s, 4); s += __shfl_xor(s, 8);
        if (l15 == 0) part[Mt * 16 + kq * 4 + r][w] = s;
      }
    __syncthreads();   // part ready
    if (tid < 64) {
      float s = part[tid][0] + part[tid][1] + part[tid][2] + part[tid][3] + b3v;
      float dd = fmaxf(s, 0.f) + log1pf(__expf(-fabsf(s)));
      dout[(long)i * 512 + j0 + tid] = dd;
    }
  }
}

// ---------------- symmetrize dist in place ----------------
__global__ __launch_bounds__(256) void sym_kernel(float* __restrict__ dist)
{
  int idx = blockIdx.x * 256 + threadIdx.x;   // < 262144
  int i = idx >> 9, j = idx & 511;
  if (i < j) {
    float a = dist[idx];
    float b = dist[(long)j * 512 + i];
    float m = 0.5f * (a + b);
    dist[idx] = m;
    dist[(long)j * 512 + i] = m;
  }
}

// ---------------- coordinate head final 256->3 ----------------
__global__ __launch_bounds__(256) void coord_kernel(
    const float* __restrict__ ct, const float* __restrict__ w2,
    const float* __restrict__ b2, float* __restrict__ out)
{
  int t = blockIdx.x * 256 + threadIdx.x;
  if (t >= 1536) return;
  int row = t / 3, c = t - row * 3;
  float s = b2[c];
  const float* a = &ct[(long)row * 256];
  const float* wp = &w2[c * 256];
  for (int k = 0; k < 256; ++k) s += a[k] * wp[k];
  out[t] = s;
}

extern "C" void kernel_launch(void* const* d_in, const int* in_sizes, int n_in,
                              void* d_out, int out_size, void* d_ws, size_t ws_size,
                              hipStream_t stream) {
  const float* z        = (const float*)d_in[0];
  const float* z_global = (const float*)d_in[1];
  const int*   atom_t   = (const int*)d_in[2];
  const float* emb      = (const float*)d_in[3];
  const float* ip_w1 = (const float*)d_in[4];  const float* ip_b1 = (const float*)d_in[5];
  const float* ip_w2 = (const float*)d_in[6];  const float* ip_b2 = (const float*)d_in[7];
  const float* gp_w1 = (const float*)d_in[8];  const float* gp_b1 = (const float*)d_in[9];
  const float* gp_w2 = (const float*)d_in[10]; const float* gp_b2 = (const float*)d_in[11];
  const float* wqkv  = (const float*)d_in[12]; const float* bqkv  = (const float*)d_in[13];
  const float* wo    = (const float*)d_in[14]; const float* bo    = (const float*)d_in[15];
  const float* ln1s  = (const float*)d_in[16]; const float* ln1b  = (const float*)d_in[17];
  const float* w1    = (const float*)d_in[18]; const float* b1    = (const float*)d_in[19];
  const float* w2    = (const float*)d_in[20]; const float* b2    = (const float*)d_in[21];
  const float* ln2s  = (const float*)d_in[22]; const float* ln2b  = (const float*)d_in[23];
  const float* dpw1  = (const float*)d_in[24]; const float* dpb1  = (const float*)d_in[25];
  const float* dpw2  = (const float*)d_in[26]; const float* dpb2  = (const float*)d_in[27];
  const float* dpw3  = (const float*)d_in[28]; const float* dpb3  = (const float*)d_in[29];
  const float* cpw1  = (const float*)d_in[30]; const float* cpb1  = (const float*)d_in[31];
  const float* cpw2  = (const float*)d_in[32]; const float* cpb2  = (const float*)d_in[33];

  char* ws = (char*)d_ws;
  bf16*  WB  = (bf16*)ws;
  float* zin = (float*)(ws + F_ZIN);
  float* g   = (float*)(ws + F_G);
  float* h   = (float*)(ws + F_H);
  float* qkv = (float*)(ws + F_QKV);
  float* S   = (float*)(ws + F_S);
  bf16*  Vt  = (bf16*)(ws + F_VT);
  float* o   = (float*)(ws + F_O);
  float* t1  = (float*)(ws + F_T1);
  float* ai  = (float*)(ws + F_AI);
  float* aj  = (float*)(ws + F_AJ);
  float* ff1 = S;                    // reuse during transformer
  bf16*  W2P = (bf16*)(ws + F_S);    // reuse after transformer (128KB)
  float* out  = (float*)d_out;
  float* xout = out;
  float* dist = out + 1536;

  convw_kernel<<<2672, 256, 0, stream>>>(ip_w1, ip_w2, wqkv, wo, w1, w2, dpw1, dpw2, cpw1, WB);
  zin_kernel<<<384, 256, 0, stream>>>(z, atom_t, emb, zin);
  gproj_kernel<<<1, 256, 0, stream>>>(z_global, gp_w1, gp_b1, gp_w2, gp_b2, g);
  gemm_kernel<1, bf16><<<dim3(8, 4, 1), 256, 0, stream>>>(zin, 192, 0, WB + WB_IPW1, 192, 0,
      ip_b1, nullptr, 0, 0, t1, 256, 0, 192);
  gemm_kernel<0, bf16><<<dim3(8, 4, 1), 256, 0, stream>>>(t1, 256, 0, WB + WB_IPW2, 256, 0,
      ip_b2, g, 0, 0, h, 256, 0, 256);

  for (int l = 0; l < 3; ++l) {
    const bf16* wq = WB + WB_QKV + (long)l * 768 * 256;
    gemm_kernel<0, bf16><<<dim3(8, 12, 1), 256, 0, stream>>>(h, 256, 0, wq, 256, 0,
        bqkv + l * 768, nullptr, 0, 0, qkv, 768, 0, 256);
    gemm_kernel<0, float><<<dim3(8, 8, 4), 256, 0, stream>>>(qkv, 768, 64, qkv + 256, 768, 64,
        nullptr, nullptr, 0, 0, S, 512, 262144, 64);
    softmax_kernel<<<dim3(512, 4), 256, 0, stream>>>(S);
    vt_kernel<<<512, 256, 0, stream>>>(qkv, Vt);
    gemm_kernel<0, bf16><<<dim3(8, 1, 4), 256, 0, stream>>>(S, 512, 262144, Vt, 512, 32768,
        nullptr, nullptr, 0, 0, o, 256, 64, 512);
    gemm_kernel<0, bf16><<<dim3(8, 4, 1), 256, 0, stream>>>(o, 256, 0,
        WB + WB_WO + (long)l * 65536, 256, 0, bo + l * 256, h, 256, 0, t1, 256, 0, 256);
    ln_kernel<<<512, 256, 0, stream>>>(t1, ln1s + l * 256, ln1b + l * 256, h);
    gemm_kernel<2, bf16><<<dim3(8, 16, 1), 256, 0, stream>>>(h, 256, 0,
        WB + WB_W1 + (long)l * 262144, 256, 0, b1 + l * 1024, nullptr, 0, 0, ff1, 1024, 0, 256);
    gemm_kernel<0, bf16><<<dim3(8, 4, 1), 256, 0, stream>>>(ff1, 1024, 0,
        WB + WB_W2 + (long)l * 262144, 1024, 0, b2 + l * 256, h, 256, 0, t1, 256, 0, 1024);
    ln_kernel<<<512, 256, 0, stream>>>(t1, ln2s + l * 256, ln2b + l * 256, h);
  }

  // ai = h @ dp_w1[:, :256]^T + b1 ; aj = h @ dp_w1[:, 256:]^T
  gemm_kernel<0, bf16><<<dim3(8, 4, 1), 256, 0, stream>>>(h, 256, 0, WB + WB_DPW1, 512, 0,
      dpb1, nullptr, 0, 0, ai, 256, 0, 256);
  gemm_kernel<0, bf16><<<dim3(8, 4, 1), 256, 0, stream>>>(h, 256, 0, WB + WB_DPW1 + 256, 512, 0,
      nullptr, nullptr, 0, 0, aj, 256, 0, 256);
  // permute W2 into fragment order (ff1/S region is dead by now)
  permw2_kernel<<<32, 256, 0, stream>>>(WB + WB_DPW2, W2P);
  pair2_kernel<<<512, 256, 0, stream>>>(ai, aj, W2P, dpb2, dpw3, dpb3, dist);
  sym_kernel<<<1024, 256, 0, stream>>>(dist);
  // coord head
  gemm_kernel<1, bf16><<<dim3(8, 4, 1), 256, 0, stream>>>(h, 256, 0, WB + WB_CPW1, 256, 0,
      cpb1, nullptr, 0, 0, t1, 256, 0, 256);
  coord_kernel<<<6, 256, 0, stream>>>(t1, cpw2, cpb2, xout);
}